// Round 11
// baseline (202.608 us; speedup 1.0000x reference)
//
#include <hip/hip_runtime.h>
#include <math.h>

// Exact IEEE semantics in the visibility path: no fma contraction anywhere.
#pragma clang fp contract(off)

#define IMG 128
#define HW (IMG * IMG)
#define NB 2
#define NV 1300
#define NF 2500
#define NFACE (NB * NF) // 5000
#define EPSF 1e-8f
#define NTILE 256       // 16x16 grid of 8x8-px tiles per batch
#define NBIN (NB * NTILE)

// ws layout (bytes):
//   vn    f32[NB*NV*3]  @ 0      (31200)  zeroed by memset
//   face  f4 [NFACE*3]  @ 31232  (240000) {E0, E1, {area,z0,z1,z2}}
//   bboxf f4 [NFACE]    @ 271232 (80000)  {minx,maxx,miny,maxy}
#define OFF_FACE 31232
#define OFF_BBOX 271232

#define DINIT 0x7F800000FFFFFFFFull // depth=+inf, fidx=~0

__global__ __launch_bounds__(256) void k_face(const float* __restrict__ verts,
                                              const int* __restrict__ faces,
                                              float* __restrict__ vn,
                                              float4* __restrict__ face,
                                              float4* __restrict__ bboxf) {
    int i = blockIdx.x * 256 + threadIdx.x;
    if (i >= NFACE) return;
    int b = (i >= NF) ? 1 : 0;
    int f = i - b * NF;
    int i0 = faces[f * 3 + 0];
    int i1 = faces[f * 3 + 1];
    int i2 = faces[f * 3 + 2];
    const float* wv = verts + (size_t)b * NV * 3;
    float v0x = wv[i0 * 3 + 0], v0y = wv[i0 * 3 + 1], v0z = wv[i0 * 3 + 2];
    float v1x = wv[i1 * 3 + 0], v1y = wv[i1 * 3 + 1], v1z = wv[i1 * 3 + 2];
    float v2x = wv[i2 * 3 + 0], v2y = wv[i2 * 3 + 1], v2z = wv[i2 * 3 + 2];
    // transform, bit-identical to ref: ndc = (12*(-vx))/(2-vz), z = 2-vz
    float z0 = 2.0f - v0z, z1 = 2.0f - v1z, z2 = 2.0f - v2z;
    float p0x = (12.0f * (-v0x)) / z0, p0y = (12.0f * v0y) / z0;
    float p1x = (12.0f * (-v1x)) / z1, p1y = (12.0f * v1y) / z1;
    float p2x = (12.0f * (-v2x)) / z2, p2y = (12.0f * v2y) / z2;

    float t1 = (p1x - p0x) * (p2y - p0y);
    float t2 = (p1y - p0y) * (p2x - p0x);
    float area = t1 - t2;
    float aabs = fabsf(area);
    float area_safe = (aabs < EPSF) ? EPSF : area;

    face[i * 3 + 0] = make_float4(p2x - p1x, p2y - p1y, p1x, p1y);
    face[i * 3 + 1] = make_float4(p0x - p2x, p0y - p2y, p2x, p2y);
    face[i * 3 + 2] = make_float4(area_safe, z0, z1, z2);

    if (aabs > EPSF) {
        bboxf[i] = make_float4(fminf(p0x, fminf(p1x, p2x)),
                               fmaxf(p0x, fmaxf(p1x, p2x)),
                               fminf(p0y, fminf(p1y, p2y)),
                               fmaxf(p0y, fmaxf(p1y, p2y)));
    } else {
        bboxf[i] = make_float4(1e30f, -1e30f, 1e30f, -1e30f); // never overlaps
    }

    // world-space face normal -> scatter to vertex normals
    float ax = v1x - v0x, ay = v1y - v0y, az = v1z - v0z;
    float bx = v2x - v0x, by = v2y - v0y, bz = v2z - v0z;
    float fnx = ay * bz - az * by;
    float fny = az * bx - ax * bz;
    float fnz = ax * by - ay * bx;
    float* vnb = vn + (size_t)b * NV * 3;
    atomicAdd(&vnb[i0 * 3 + 0], fnx);
    atomicAdd(&vnb[i0 * 3 + 1], fny);
    atomicAdd(&vnb[i0 * 3 + 2], fnz);
    atomicAdd(&vnb[i1 * 3 + 0], fnx);
    atomicAdd(&vnb[i1 * 3 + 1], fny);
    atomicAdd(&vnb[i1 * 3 + 2], fnz);
    atomicAdd(&vnb[i2 * 3 + 0], fnx);
    atomicAdd(&vnb[i2 * 3 + 1], fny);
    atomicAdd(&vnb[i2 * 3 + 2], fnz);
}

// Fused bin+raster+shade. Block = one 8x8-px tile of one batch. 10 rounds:
// 256 threads bbox+SAT-test 256 faces, ballot-compact survivors into LDS;
// 4 waves raster the list strided (lane = pixel, face broadcast from LDS),
// per-pixel best in register. Final: 4-way LDS merge, wave 0 shades+stores.
// No global bins/dbuf, no atomics. Batch 1's tile is offset by (8,8) tiles
// so both batches' hot central tiles land on different CUs.
__global__ __launch_bounds__(256) void k_fused(const float* __restrict__ verts,
                                               const int* __restrict__ faces,
                                               const float* __restrict__ vn,
                                               const float4* __restrict__ face,
                                               const float4* __restrict__ bboxf,
                                               float* __restrict__ out) {
    __shared__ float4 sE0[256], sE1[256], sFD[256];
    __shared__ int sid[256];
    __shared__ int wbase[4];
    __shared__ int scnt;
    __shared__ unsigned long long sbest[4][64];

    int b = blockIdx.x >> 8;
    int tile = blockIdx.x & 255;
    if (b) tile = (tile + 136) & 255; // (row+8, col+8) offset for batch 1
    int tr = tile >> 4, tc = tile & 15;
    float x_hi = 1.0f - (2.0f * (float)(tc * 8) + 1.0f) / 128.0f;
    float x_lo = 1.0f - (2.0f * (float)(tc * 8 + 7) + 1.0f) / 128.0f;
    float y_hi = 1.0f - (2.0f * (float)(tr * 8) + 1.0f) / 128.0f;
    float y_lo = 1.0f - (2.0f * (float)(tr * 8 + 7) + 1.0f) / 128.0f;

    int t = threadIdx.x, wid = t >> 6, lane = t & 63;
    int r = tr * 8 + (lane >> 3);
    int c = tc * 8 + (lane & 7);
    float px = 1.0f - (2.0f * (float)c + 1.0f) / 128.0f;
    float py = 1.0f - (2.0f * (float)r + 1.0f) / 128.0f;

    unsigned long long best = DINIT;
    for (int base = 0; base < NF; base += 256) {
        int f = base + t;
        bool pass = false;
        float4 E0, E1, FD;
        if (f < NF) {
            int i = b * NF + f;
            float4 bb = bboxf[i];
            if (bb.y >= x_lo - 0.02f && bb.x <= x_hi + 0.02f &&
                bb.w >= y_lo - 0.02f && bb.z <= y_hi + 0.02f) {
                E0 = face[i * 3 + 0];
                E1 = face[i * 3 + 1];
                FD = face[i * 3 + 2];
                float as = FD.x;
                float s = (as > 0.0f) ? 1.0f : -1.0f;
                float mg0 = 1e-3f * (1.0f + fabsf(E0.x) + fabsf(E0.y));
                float mg1 = 1e-3f * (1.0f + fabsf(E1.x) + fabsf(E1.y));
                float mg2 = mg0 + mg1 + 1e-6f;
                float a0a = s * E0.x * (y_lo - E0.w), a0b = s * E0.x * (y_hi - E0.w);
                float b0a = -s * E0.y * (x_lo - E0.z), b0b = -s * E0.y * (x_hi - E0.z);
                float max0 = fmaxf(a0a, a0b) + fmaxf(b0a, b0b);
                float min0 = fminf(a0a, a0b) + fminf(b0a, b0b);
                float a1a = s * E1.x * (y_lo - E1.w), a1b = s * E1.x * (y_hi - E1.w);
                float b1a = -s * E1.y * (x_lo - E1.z), b1b = -s * E1.y * (x_hi - E1.z);
                float max1 = fmaxf(a1a, a1b) + fmaxf(b1a, b1b);
                float min1 = fminf(a1a, a1b) + fminf(b1a, b1b);
                pass = (max0 >= -mg0) && (max1 >= -mg1) &&
                       ((s * as - min0 - min1) >= -mg2);
            }
        }
        unsigned long long m = __ballot(pass);
        if (lane == 0) wbase[wid] = __popcll(m);
        __syncthreads();
        int myb = 0;
        for (int w2 = 0; w2 < wid; ++w2) myb += wbase[w2];
        if (pass) {
            int pos = myb + __popcll(m & ((1ull << lane) - 1ull));
            sE0[pos] = E0; sE1[pos] = E1; sFD[pos] = FD;
            sid[pos] = f;
        }
        if (t == 0) scnt = 0;
        __syncthreads();
        if (t == 0) scnt = wbase[0] + wbase[1] + wbase[2] + wbase[3];
        __syncthreads();
        int cnt = scnt;

        for (int j = wid; j < cnt; j += 4) {
            float4 fE0 = sE0[j], fE1 = sE1[j], fFD = sFD[j];
            int ff = sid[j];
            float as = fFD.x;
            // exact ref order: e = (bx-ax)*(py-ay) - (by-ay)*(px-ax)
            float u1 = fE0.x * (py - fE0.w);
            float u2 = fE0.y * (px - fE0.z);
            float e0 = u1 - u2;
            float u3 = fE1.x * (py - fE1.w);
            float u4 = fE1.y * (px - fE1.z);
            float e1 = u3 - u4;
            bool ok = (as > 0.0f) ? (e0 >= 0.0f && e1 >= 0.0f)
                                  : (e0 <= 0.0f && e1 <= 0.0f);
            if (__any(ok)) {
                float b0 = e0 / as; // true IEEE division, as in ref
                float b1 = e1 / as;
                float b2 = (1.0f - b0) - b1;
                float S = ((b0 / fFD.y) + (b1 / fFD.z)) + (b2 / fFD.w);
                if (ok && b2 >= 0.0f && S > EPSF) {
                    float depth = 1.0f / fmaxf(S, EPSF);
                    unsigned long long pk =
                        ((unsigned long long)__float_as_uint(depth) << 32) |
                        (unsigned)ff;
                    if (pk < best) best = pk;
                }
            }
        }
        __syncthreads(); // protect LDS before next round's compaction
    }

    sbest[wid][lane] = best;
    __syncthreads();
    if (wid != 0) return;

    unsigned long long pk = sbest[0][lane];
    if (sbest[1][lane] < pk) pk = sbest[1][lane];
    if (sbest[2][lane] < pk) pk = sbest[2][lane];
    if (sbest[3][lane] < pk) pk = sbest[3][lane];

    unsigned dbits = (unsigned)(pk >> 32);
    bool hit = dbits < 0x7F800000u;
    float cr = 255.0f, cg = 255.0f, cb = 255.0f, alpha = 0.0f;
    if (hit) {
        alpha = 1.0f;
        int f = (int)(unsigned)(pk & 0xFFFFFFFFull);
        int i0 = faces[f * 3 + 0];
        int i1 = faces[f * 3 + 1];
        int i2 = faces[f * 3 + 2];
        const float* wv = verts + (size_t)b * NV * 3;
        float v0x = wv[i0 * 3 + 0], v0y = wv[i0 * 3 + 1], v0z = wv[i0 * 3 + 2];
        float v1x = wv[i1 * 3 + 0], v1y = wv[i1 * 3 + 1], v1z = wv[i1 * 3 + 2];
        float v2x = wv[i2 * 3 + 0], v2y = wv[i2 * 3 + 1], v2z = wv[i2 * 3 + 2];
        float z0 = 2.0f - v0z, z1 = 2.0f - v1z, z2 = 2.0f - v2z;
        float a0x = (12.0f * (-v0x)) / z0, a0y = (12.0f * v0y) / z0;
        float a1x = (12.0f * (-v1x)) / z1, a1y = (12.0f * v1y) / z1;
        float a2x = (12.0f * (-v2x)) / z2, a2y = (12.0f * v2y) / z2;

        float t1 = (a1x - a0x) * (a2y - a0y);
        float t2 = (a1y - a0y) * (a2x - a0x);
        float ar = t1 - t2;
        ar = (fabsf(ar) < EPSF) ? EPSF : ar;
        float u1 = (a2x - a1x) * (py - a1y);
        float u2 = (a2y - a1y) * (px - a1x);
        float bb0 = (u1 - u2) / ar;
        float u3 = (a0x - a2x) * (py - a2y);
        float u4 = (a0y - a2y) * (px - a2x);
        float bb1 = (u3 - u4) / ar;
        float bb2 = (1.0f - bb0) - bb1;
        float w0 = bb0 / z0;
        float w1 = bb1 / z1;
        float w2 = bb2 / z2;
        float denom = ((w0 + w1) + w2) + EPSF;
        float pc0 = w0 / denom;
        float pc1 = w1 / denom;
        float pc2 = w2 / denom;

        float posx = (pc0 * v0x + pc1 * v1x) + pc2 * v2x;
        float posy = (pc0 * v0y + pc1 * v1y) + pc2 * v2y;
        float posz = (pc0 * v0z + pc1 * v1z) + pc2 * v2z;

        const float* vnb = vn + (size_t)b * NV * 3;
        float n0x = vnb[i0 * 3 + 0], n0y = vnb[i0 * 3 + 1], n0z = vnb[i0 * 3 + 2];
        float n1x = vnb[i1 * 3 + 0], n1y = vnb[i1 * 3 + 1], n1z = vnb[i1 * 3 + 2];
        float n2x = vnb[i2 * 3 + 0], n2y = vnb[i2 * 3 + 1], n2z = vnb[i2 * 3 + 2];
        float in0 = 1.0f / (sqrtf(n0x * n0x + n0y * n0y + n0z * n0z) + EPSF);
        float in1 = 1.0f / (sqrtf(n1x * n1x + n1y * n1y + n1z * n1z) + EPSF);
        float in2 = 1.0f / (sqrtf(n2x * n2x + n2y * n2y + n2z * n2z) + EPSF);
        n0x *= in0; n0y *= in0; n0z *= in0;
        n1x *= in1; n1y *= in1; n1z *= in1;
        n2x *= in2; n2y *= in2; n2z *= in2;
        float nx = (pc0 * n0x + pc1 * n1x) + pc2 * n2x;
        float ny = (pc0 * n0y + pc1 * n1y) + pc2 * n2y;
        float nz = (pc0 * n0z + pc1 * n1z) + pc2 * n2z;
        float inn = 1.0f / (sqrtf(nx * nx + ny * ny + nz * nz) + EPSF);
        nx *= inn; ny *= inn; nz *= inn;

        float lx = 0.0f - posx, ly = 1.0f - posy, lz = 3.0f - posz;
        float iln = 1.0f / (sqrtf(lx * lx + ly * ly + lz * lz) + EPSF);
        lx *= iln; ly *= iln; lz *= iln;
        float vx = 0.0f - posx, vy = 0.0f - posy, vz = 2.0f - posz;
        float ivn = 1.0f / (sqrtf(vx * vx + vy * vy + vz * vz) + EPSF);
        vx *= ivn; vy *= ivn; vz *= ivn;

        float ndl = nx * lx + ny * ly + nz * lz;
        float ndlr = fmaxf(ndl, 0.0f);
        float rx = 2.0f * ndl * nx - lx;
        float ry = 2.0f * ndl * ny - ly;
        float rz = 2.0f * ndl * nz - lz;
        float sc = fmaxf(rx * vx + ry * vy + rz * vz, 0.0f);
        float spec = 0.2f * 0.6f * powf(sc, 10.0f);
        float shade = 0.5f * 1.0f + 0.3f * 1.0f * ndlr;
        cr = ((142.0f / 255.0f) * shade + spec) * 255.0f;
        cg = ((179.0f / 255.0f) * shade + spec) * 255.0f;
        cb = ((247.0f / 255.0f) * shade + spec) * 255.0f;
    }
    int p = r * IMG + c;
    float* img = out + (size_t)b * 3 * HW;
    img[0 * HW + p] = cr;
    img[1 * HW + p] = cg;
    img[2 * HW + p] = cb;
    out[(size_t)NB * 3 * HW + (size_t)b * HW + p] = alpha;
}

extern "C" void kernel_launch(void* const* d_in, const int* in_sizes, int n_in,
                              void* d_out, int out_size, void* d_ws, size_t ws_size,
                              hipStream_t stream) {
    const float* verts = (const float*)d_in[0]; // [NB, NV, 3]
    const int* faces = (const int*)d_in[1];     // [NF, 3]
    char* ws = (char*)d_ws;
    float* vn = (float*)(ws + 0);
    float4* face = (float4*)(ws + OFF_FACE);
    float4* bboxf = (float4*)(ws + OFF_BBOX);
    float* out = (float*)d_out;

    hipMemsetAsync(vn, 0, NB * NV * 3 * sizeof(float), stream);
    k_face<<<(NFACE + 255) / 256, 256, 0, stream>>>(verts, faces, vn, face, bboxf);
    k_fused<<<NBIN, 256, 0, stream>>>(verts, faces, vn, face, bboxf, out);
}